// Round 8
// baseline (325.372 us; speedup 1.0000x reference)
//
#include <hip/hip_runtime.h>

typedef unsigned short u16;
typedef __bf16 bf16x8 __attribute__((ext_vector_type(8)));
typedef float f32x4 __attribute__((ext_vector_type(4)));

#define MFMA16 __builtin_amdgcn_mfma_f32_16x16x32_bf16

constexpr int NB = 2, TS = 2048, HD = 1024, NH = 16, DH = 64;
// SCALE * log2(e): folded into Wq/bq so softmax uses raw exp2
constexpr float ALPHA = 0.045084220027780106f;

__device__ __forceinline__ u16 f2bf(float f) {
    union { float f; unsigned u; } v; v.f = f;
    unsigned r = v.u + 0x7FFFu + ((v.u >> 16) & 1u);  // RNE
    return (u16)(r >> 16);
}
__device__ __forceinline__ float bf2f(u16 h) {
    union { unsigned u; float f; } v; v.u = ((unsigned)h) << 16;
    return v.f;
}
__device__ __forceinline__ bf16x8 ldb8(const u16* p) {
    return *reinterpret_cast<const bf16x8*>(p);
}
__device__ __forceinline__ void glds16(const u16* g, u16* l) {
    __builtin_amdgcn_global_load_lds(
        (const __attribute__((address_space(1))) unsigned int*)g,
        (__attribute__((address_space(3))) unsigned int*)l, 16, 0, 0);
}

#if defined(__has_builtin)
#  if __has_builtin(__builtin_amdgcn_cvt_pk_bf16_f32)
#    define HAVE_PKBF16 1
#  endif
#  if __has_builtin(__builtin_amdgcn_exp2f)
#    define HAVE_EXP2 1
#  endif
#endif
#ifndef HAVE_PKBF16
#  define HAVE_PKBF16 0
#endif
#ifndef HAVE_EXP2
#  define HAVE_EXP2 0
#endif
__device__ __forceinline__ unsigned pk2(float a, float b) {
#if HAVE_PKBF16
    typedef __bf16 bf16x2 __attribute__((ext_vector_type(2)));
    bf16x2 r = __builtin_amdgcn_cvt_pk_bf16_f32(a, b);
    return __builtin_bit_cast(unsigned, r);
#else
    return (unsigned)f2bf(a) | ((unsigned)f2bf(b) << 16);
#endif
}
__device__ __forceinline__ float fexp2(float x) {
#if HAVE_EXP2
    return __builtin_amdgcn_exp2f(x);
#else
    return exp2f(x);
#endif
}

// ------- prep: z<3: fp32->bf16 convert q/k/v; z==3: weight transpose ----
// grid (2048, 1, 4), block 256.
__global__ __launch_bounds__(256) void prep(
    const float* __restrict__ a0, const float* __restrict__ a1, const float* __restrict__ a2,
    u16* __restrict__ o0, u16* __restrict__ o1, u16* __restrict__ o2,
    const float* __restrict__ w0, const float* __restrict__ w1,
    const float* __restrict__ w2, const float* __restrict__ w3,
    u16* __restrict__ wo0, u16* __restrict__ wo1,
    u16* __restrict__ wo2, u16* __restrict__ wo3)
{
    __shared__ __align__(16) u16 tile[64 * 72];
    if (blockIdx.z < 3) {
        const float* s; u16* d;
        if (blockIdx.z == 0)      { s = a0; d = o0; }
        else if (blockIdx.z == 1) { s = a1; d = o1; }
        else                      { s = a2; d = o2; }
        size_t i = ((size_t)blockIdx.x * 256 + threadIdx.x) * 8;
        float4 v0 = *reinterpret_cast<const float4*>(s + i);
        float4 v1 = *reinterpret_cast<const float4*>(s + i + 4);
        uint4 w = { pk2(v0.x, v0.y), pk2(v0.z, v0.w), pk2(v1.x, v1.y), pk2(v1.z, v1.w) };
        *reinterpret_cast<uint4*>(d + i) = w;
        return;
    }
    if (blockIdx.x >= 1024) return;
    const int wi = blockIdx.x >> 8, ti = blockIdx.x & 255;
    const int ky = ti >> 4, nx = ti & 15;
    const float* src; u16* dst; float sc = 1.0f;
    if (wi == 0)      { src = w0; dst = wo0; sc = ALPHA; }
    else if (wi == 1) { src = w1; dst = wo1; }
    else if (wi == 2) { src = w2; dst = wo2; }
    else              { src = w3; dst = wo3; }
    const int k0 = ky * 64, n0 = nx * 64;
    const int t = threadIdx.x, r = t >> 2, c0 = (t & 3) << 4;
#pragma unroll
    for (int j = 0; j < 4; ++j) {
        float4 v = *reinterpret_cast<const float4*>(&src[(size_t)(k0 + r) * HD + n0 + c0 + 4 * j]);
        tile[(c0 + 4 * j + 0) * 72 + r] = f2bf(v.x * sc);
        tile[(c0 + 4 * j + 1) * 72 + r] = f2bf(v.y * sc);
        tile[(c0 + 4 * j + 2) * 72 + r] = f2bf(v.z * sc);
        tile[(c0 + 4 * j + 3) * 72 + r] = f2bf(v.w * sc);
    }
    __syncthreads();
#pragma unroll
    for (int j = 0; j < 2; ++j)
        *reinterpret_cast<uint4*>(&dst[(size_t)(n0 + r) * HD + k0 + c0 + 8 * j]) =
            *reinterpret_cast<const uint4*>(&tile[r * 72 + c0 + 8 * j]);
}

// -------- merged Q/K/V projection GEMM, 128x128 tile, BK=64 -------------
// XOR-swizzled LDS (row stride 64, chunk ^ (row&7)) — conflict-free b128.
__global__ __launch_bounds__(256) void gemm_qkv(
    const u16* __restrict__ A0, const u16* __restrict__ A1, const u16* __restrict__ A2,
    const u16* __restrict__ B0, const u16* __restrict__ B1, const u16* __restrict__ B2,
    const float* __restrict__ c0, const float* __restrict__ c1, const float* __restrict__ c2,
    u16* __restrict__ C0, u16* __restrict__ C1, u16* __restrict__ C2)
{
    const u16 *A, *BT; const float* bias; u16* C; float bsc;
    if (blockIdx.z == 0)      { A = A0; BT = B0; bias = c0; C = C0; bsc = ALPHA; }
    else if (blockIdx.z == 1) { A = A1; BT = B1; bias = c1; C = C1; bsc = 1.0f; }
    else                      { A = A2; BT = B2; bias = c2; C = C2; bsc = 1.0f; }
    constexpr int N = HD, K = HD;
    __shared__ __align__(16) u16 As[128 * 64];
    __shared__ __align__(16) u16 Bs[128 * 64];
    const int m0 = blockIdx.y * 128, n0 = blockIdx.x * 128;
    const int tid = threadIdx.x, wid = tid >> 6, lane = tid & 63;
    const int q = lane >> 4, c = lane & 15;
    const int wm = wid >> 1, wn = wid & 1;
    const int r = tid >> 3, ch = tid & 7;
    const int xc = (ch ^ (r & 7)) << 3;
    const u16* ag = A + (size_t)(m0 + r) * K + xc;
    const u16* bg = BT + (size_t)(n0 + r) * K + xc;
    f32x4 acc[4][4] = {};
    for (int k0 = 0; k0 < K; k0 += 64) {
#pragma unroll
        for (int L = 0; L < 4; ++L) {
            glds16(ag + (size_t)(32 * L) * K, &As[L * 2048 + tid * 8]);
            glds16(bg + (size_t)(32 * L) * K, &Bs[L * 2048 + tid * 8]);
        }
        ag += 64; bg += 64;
        __syncthreads();
        bf16x8 af[4][2], bf[4][2];
#pragma unroll
        for (int i = 0; i < 4; ++i)
#pragma unroll
            for (int kk = 0; kk < 2; ++kk) {
                af[i][kk] = ldb8(&As[(wm * 64 + i * 16 + c) * 64 + (((kk * 4 + q) ^ (c & 7)) << 3)]);
                bf[i][kk] = ldb8(&Bs[(wn * 64 + i * 16 + c) * 64 + (((kk * 4 + q) ^ (c & 7)) << 3)]);
            }
#pragma unroll
        for (int kk = 0; kk < 2; ++kk)
#pragma unroll
            for (int i = 0; i < 4; ++i)
#pragma unroll
                for (int jn = 0; jn < 4; ++jn)
                    acc[i][jn] = MFMA16(bf[jn][kk], af[i][kk], acc[i][jn], 0, 0, 0);
        __syncthreads();
    }
#pragma unroll
    for (int i = 0; i < 4; ++i)
#pragma unroll
        for (int jn = 0; jn < 4; ++jn) {
            int row = m0 + wm * 64 + i * 16 + c;
            int col = n0 + wn * 64 + jn * 16 + q * 4;
            float4 bb = *reinterpret_cast<const float4*>(&bias[col]);
            uint2 w = { pk2(acc[i][jn][0] + bb.x * bsc, acc[i][jn][1] + bb.y * bsc),
                        pk2(acc[i][jn][2] + bb.z * bsc, acc[i][jn][3] + bb.w * bsc) };
            *reinterpret_cast<uint2*>(&C[(size_t)row * N + col]) = w;
        }
}

// ---------------- V transpose per head: VT[nh][d][tau] ------------------
__global__ __launch_bounds__(256) void vtrans(const u16* __restrict__ V, u16* __restrict__ VT)
{
    __shared__ __align__(16) u16 tile[64 * 72];
    const int nh = blockIdx.y, t0 = blockIdx.x * 64;
    const u16* src = V + (size_t)nh * TS * DH;
    u16* dst = VT + (size_t)nh * DH * TS;
    const int t = threadIdx.x, r = t >> 2, c0 = (t & 3) << 4;
    *reinterpret_cast<uint4*>(&tile[r * 72 + c0]) =
        *reinterpret_cast<const uint4*>(&src[(size_t)(t0 + r) * DH + c0]);
    *reinterpret_cast<uint4*>(&tile[r * 72 + c0 + 8]) =
        *reinterpret_cast<const uint4*>(&src[(size_t)(t0 + r) * DH + c0 + 8]);
    __syncthreads();
    const int d = t >> 2, tc = (t & 3) << 4;
    u16 tmp[16];
#pragma unroll
    for (int j = 0; j < 16; ++j) tmp[j] = tile[(tc + j) * 72 + d];
    *reinterpret_cast<uint4*>(&dst[(size_t)d * TS + t0 + tc]) = *reinterpret_cast<const uint4*>(&tmp[0]);
    *reinterpret_cast<uint4*>(&dst[(size_t)d * TS + t0 + tc + 8]) = *reinterpret_cast<const uint4*>(&tmp[8]);
}

// -------- final GEMM: C[M,N](f32) = A @ BT^T + bias, 64x128, BK=64 ------
__global__ __launch_bounds__(256) void gemm_out(
    const u16* __restrict__ A, const u16* __restrict__ BT,
    const float* __restrict__ bias, float* __restrict__ C,
    int M, int N, int K)
{
    __shared__ __align__(16) u16 As[64 * 64];
    __shared__ __align__(16) u16 Bs[128 * 64];
    const int m0 = blockIdx.y * 64, n0 = blockIdx.x * 128;
    const int tid = threadIdx.x, wid = tid >> 6, lane = tid & 63;
    const int q = lane >> 4, c = lane & 15;
    const int wm = wid >> 1, wn = wid & 1;
    const int r = tid >> 3, ch = tid & 7;
    const int xc = (ch ^ (r & 7)) << 3;
    const u16* ag = A + (size_t)(m0 + r) * K + xc;
    const u16* bg = BT + (size_t)(n0 + r) * K + xc;
    f32x4 acc[2][4] = {};
    for (int k0 = 0; k0 < K; k0 += 64) {
        glds16(ag, &As[tid * 8]);
        glds16(ag + (size_t)32 * K, &As[2048 + tid * 8]);
#pragma unroll
        for (int L = 0; L < 4; ++L)
            glds16(bg + (size_t)(32 * L) * K, &Bs[L * 2048 + tid * 8]);
        ag += 64; bg += 64;
        __syncthreads();
        bf16x8 af[2][2], bf[4][2];
#pragma unroll
        for (int jm = 0; jm < 2; ++jm)
#pragma unroll
            for (int kk = 0; kk < 2; ++kk)
                af[jm][kk] = ldb8(&As[(wm * 32 + jm * 16 + c) * 64 + (((kk * 4 + q) ^ (c & 7)) << 3)]);
#pragma unroll
        for (int jn = 0; jn < 4; ++jn)
#pragma unroll
            for (int kk = 0; kk < 2; ++kk)
                bf[jn][kk] = ldb8(&Bs[(wn * 64 + jn * 16 + c) * 64 + (((kk * 4 + q) ^ (c & 7)) << 3)]);
#pragma unroll
        for (int kk = 0; kk < 2; ++kk)
#pragma unroll
            for (int jm = 0; jm < 2; ++jm)
#pragma unroll
                for (int jn = 0; jn < 4; ++jn)
                    acc[jm][jn] = MFMA16(bf[jn][kk], af[jm][kk], acc[jm][jn], 0, 0, 0);
        __syncthreads();
    }
#pragma unroll
    for (int jm = 0; jm < 2; ++jm)
#pragma unroll
        for (int jn = 0; jn < 4; ++jn) {
            int row = m0 + wm * 32 + jm * 16 + c;
            int col = n0 + wn * 64 + jn * 16 + q * 4;
            float4 bb = *reinterpret_cast<const float4*>(&bias[col]);
            float4 v = { acc[jm][jn][0] + bb.x, acc[jm][jn][1] + bb.y,
                         acc[jm][jn][2] + bb.z, acc[jm][jn][3] + bb.w };
            *reinterpret_cast<float4*>(&C[(size_t)row * N + col]) = v;
        }
}

// -------- pass 1: Zf = 1/sum_h exp2(S'), frag-row layout ----------------
// grid (32 sb, 16 tb, 2 n); t128. Q frags direct from global; K dbuf,
// single barrier per head-iter (staging of h+1 overlaps compute of h).
__global__ __launch_bounds__(256) void z_kernel(
    const u16* __restrict__ Qp, const u16* __restrict__ Kp, u16* __restrict__ Zf)
{
    __shared__ __align__(16) u16 Ks[2 * 64 * 64];
    const int sb = blockIdx.x, tb = blockIdx.y, n = blockIdx.z;
    const int s0 = sb * 64, t0 = tb * 128;
    const int tid = threadIdx.x, wid = tid >> 6, lane = tid & 63;
    const int q = lane >> 4, c = lane & 15;
    const int krow = tid >> 3, kch = tid & 7;
    const int xsw = (kch ^ (krow & 7)) << 3;
    const u16* kg = Kp + (size_t)(n * NH) * TS * DH + (size_t)(s0 + krow) * DH + xsw;
    const u16* Qh = Qp + (size_t)(n * NH) * TS * DH;
    // preload h=0 into buf 0
    glds16(kg, &Ks[tid * 8]);
    glds16(kg + (size_t)32 * DH, &Ks[2048 + tid * 8]);
    kg += (size_t)TS * DH;
    float zacc[2][4][4] = {};
    for (int h = 0; h < NH; ++h) {
        u16* Kc = &Ks[(h & 1) * 4096];
        __syncthreads();                    // staging for h complete
        if (h + 1 < NH) {
            u16* Kn = &Ks[((h + 1) & 1) * 4096];
            glds16(kg, &Kn[tid * 8]);
            glds16(kg + (size_t)32 * DH, &Kn[2048 + tid * 8]);
            kg += (size_t)TS * DH;
        }
        bf16x8 qa[2][2], kb[4][2];
#pragma unroll
        for (int jm = 0; jm < 2; ++jm)
#pragma unroll
            for (int kf = 0; kf < 2; ++kf)
                qa[jm][kf] = ldb8(&Qh[(size_t)(t0 + wid * 32 + jm * 16 + c) * DH + kf * 32 + q * 8]);
#pragma unroll
        for (int i = 0; i < 4; ++i)
#pragma unroll
            for (int kf = 0; kf < 2; ++kf)
                kb[i][kf] = ldb8(&Kc[(i * 16 + c) * 64 + (((kf * 4 + q) ^ (c & 7)) << 3)]);
        f32x4 s_[2][4] = {};
#pragma unroll
        for (int kf = 0; kf < 2; ++kf)
#pragma unroll
            for (int jm = 0; jm < 2; ++jm)
#pragma unroll
                for (int i = 0; i < 4; ++i)
                    s_[jm][i] = MFMA16(kb[i][kf], qa[jm][kf], s_[jm][i], 0, 0, 0);
#pragma unroll
        for (int jm = 0; jm < 2; ++jm)
#pragma unroll
            for (int i = 0; i < 4; ++i)
#pragma unroll
                for (int r = 0; r < 4; ++r)
                    zacc[jm][i][r] += fexp2(s_[jm][i][r]);
        Qh += (size_t)TS * DH;
    }
#pragma unroll
    for (int jm = 0; jm < 2; ++jm) {
        int t = t0 + wid * 32 + jm * 16 + c;
        size_t zb = ((size_t)((n * 32 + sb) * 2048) + t) * 64 + q * 16;
        unsigned w32[8];
#pragma unroll
        for (int i = 0; i < 4; ++i) {
            w32[i * 2 + 0] = pk2(1.0f / zacc[jm][i][0], 1.0f / zacc[jm][i][1]);
            w32[i * 2 + 1] = pk2(1.0f / zacc[jm][i][2], 1.0f / zacc[jm][i][3]);
        }
        *reinterpret_cast<uint4*>(&Zf[zb])     = *reinterpret_cast<const uint4*>(&w32[0]);
        *reinterpret_cast<uint4*>(&Zf[zb + 8]) = *reinterpret_cast<const uint4*>(&w32[4]);
    }
}

// -------- pass 2: out2[h] = (exp2(S') * Zinv) @ V[h] --------------------
// grid (32 tb, 16 h, 2 n); t64. K/V double-buffered, single barrier/iter.
__global__ __launch_bounds__(256) void attn_kernel(
    const u16* __restrict__ Qp, const u16* __restrict__ Kp, const u16* __restrict__ VT,
    const u16* __restrict__ Zf, u16* __restrict__ o2)
{
    __shared__ __align__(16) u16 Ks[2 * 64 * 64];
    __shared__ __align__(16) u16 Vs[2 * 64 * 64];
    __shared__ __align__(16) u16 Ps[64 * 72];   // [t][s], wave-private 16-row bands
    const int tb = blockIdx.x, h = blockIdx.y, n = blockIdx.z;
    const int t0 = tb * 64;
    const int tid = threadIdx.x, wid = tid >> 6, lane = tid & 63;
    const int q = lane >> 4, c = lane & 15;
    const int krow = tid >> 3, kch = tid & 7;
    const int xsw = (kch ^ (krow & 7)) << 3;
    const size_t base = (size_t)(n * NH + h) * TS * DH;
    const int tme = t0 + wid * 16 + c;
    bf16x8 qa[2];
#pragma unroll
    for (int kf = 0; kf < 2; ++kf)
        qa[kf] = ldb8(&Qp[base + (size_t)tme * DH + kf * 32 + q * 8]);
    const u16* kg = Kp + base + (size_t)krow * DH + xsw;
    const u16* vg = VT + base + (size_t)krow * TS + xsw;
    const u16* zg = Zf + ((size_t)(n * 32) * 2048 + tme) * 64 + q * 16;
    // preload sb=0 into buf 0
    glds16(kg, &Ks[tid * 8]);
    glds16(kg + (size_t)32 * DH, &Ks[2048 + tid * 8]);
    glds16(vg, &Vs[tid * 8]);
    glds16(vg + (size_t)32 * TS, &Vs[2048 + tid * 8]);
    kg += 64 * DH; vg += 64;
    f32x4 oacc[4] = {};
    for (int sb = 0; sb < 32; ++sb) {
        u16* Kc = &Ks[(sb & 1) * 4096];
        u16* Vc = &Vs[(sb & 1) * 4096];
        __syncthreads();                    // staging for sb complete
        if (sb + 1 < 32) {
            u16* Kn = &Ks[((sb + 1) & 1) * 4096];
            u16* Vn = &Vs[((sb + 1) & 1) * 4096];
            glds16(kg, &Kn[tid * 8]);
            glds16(kg + (size_t)32 * DH, &Kn[2048 + tid * 8]);
            glds16(vg, &Vn[tid * 8]);
            glds16(vg + (size_t)32 * TS, &Vn[2048 + tid * 8]);
            kg += 64 * DH; vg += 64;
        }
        u16 zl[16];
        *reinterpret_cast<uint4*>(&zl[0]) = *reinterpret_cast<const uint4*>(zg);
        *reinterpret_cast<uint4*>(&zl[8]) = *reinterpret_cast<const uint4*>(zg + 8);
        zg += (size_t)2048 * 64;
        bf16x8 kb[4][2];
#pragma unroll
        for (int i = 0; i < 4; ++i)
#pragma unroll
            for (int kf = 0; kf < 2; ++kf)
                kb[i][kf] = ldb8(&Kc[(i * 16 + c) * 64 + (((kf * 4 + q) ^ (c & 7)) << 3)]);
        f32x4 s_[4] = {};
#pragma unroll
        for (int kf = 0; kf < 2; ++kf)
#pragma unroll
            for (int i = 0; i < 4; ++i)
                s_[i] = MFMA16(kb[i][kf], qa[kf], s_[i], 0, 0, 0);
#pragma unroll
        for (int i = 0; i < 4; ++i) {
            float p0 = fexp2(s_[i][0]) * bf2f(zl[i * 4 + 0]);
            float p1 = fexp2(s_[i][1]) * bf2f(zl[i * 4 + 1]);
            float p2 = fexp2(s_[i][2]) * bf2f(zl[i * 4 + 2]);
            float p3 = fexp2(s_[i][3]) * bf2f(zl[i * 4 + 3]);
            uint2 w = { pk2(p0, p1), pk2(p2, p3) };
            *reinterpret_cast<uint2*>(&Ps[(wid * 16 + c) * 72 + i * 16 + q * 4]) = w;
        }
        bf16x8 pa[2], vb[4][2];
#pragma unroll
        for (int kf = 0; kf < 2; ++kf)
            pa[kf] = ldb8(&Ps[(wid * 16 + c) * 72 + kf * 32 + q * 8]);
#pragma unroll
        for (int dn = 0; dn < 4; ++dn)
#pragma unroll
            for (int kf = 0; kf < 2; ++kf)
                vb[dn][kf] = ldb8(&Vc[(dn * 16 + c) * 64 + (((kf * 4 + q) ^ (c & 7)) << 3)]);
#pragma unroll
        for (int kf = 0; kf < 2; ++kf)
#pragma unroll
            for (int dn = 0; dn < 4; ++dn)
                oacc[dn] = MFMA16(vb[dn][kf], pa[kf], oacc[dn], 0, 0, 0);
    }
#pragma unroll
    for (int dn = 0; dn < 4; ++dn) {
        uint2 w = { pk2(oacc[dn][0], oacc[dn][1]), pk2(oacc[dn][2], oacc[dn][3]) };
        *reinterpret_cast<uint2*>(&o2[base + (size_t)tme * DH + dn * 16 + q * 4]) = w;
    }
}

extern "C" void kernel_launch(void* const* d_in, const int* in_sizes, int n_in,
                              void* d_out, int out_size, void* d_ws, size_t ws_size,
                              hipStream_t stream)
{
    const float* q  = (const float*)d_in[0];
    const float* k  = (const float*)d_in[1];
    const float* v  = (const float*)d_in[2];
    const float* Wq = (const float*)d_in[3];
    const float* bq = (const float*)d_in[4];
    const float* Wk = (const float*)d_in[5];
    const float* bk = (const float*)d_in[6];
    const float* Wv = (const float*)d_in[7];
    const float* bv = (const float*)d_in[8];
    const float* Wo = (const float*)d_in[9];
    const float* bo = (const float*)d_in[10];
    float* out = (float*)d_out;

    // ws (u16 elems), 56 MiB: wT x4 (2 MiB) + S1..S6 (8 MiB each)
    //   qb=S1 kb=S2 vb=S3 (live through gemm_qkv)  Qp=S4 Kp=S5 Vp=S6
    //   VTb=S1 (qb dead)  Zf=S2..S3 (16 MiB, kb/vb dead)  o2=S6 (Vp dead)
    u16* ws  = (u16*)d_ws;
    u16* wqT = ws + 0 * 1048576;
    u16* wkT = ws + 1 * 1048576;
    u16* wvT = ws + 2 * 1048576;
    u16* woT = ws + 3 * 1048576;
    u16* S1  = ws + 4194304;
    u16* S2  = S1 + 4194304;
    u16* S3  = S2 + 4194304;
    u16* S4  = S3 + 4194304;
    u16* S5  = S4 + 4194304;
    u16* S6  = S5 + 4194304;
    u16 *qb = S1, *kb = S2, *vb = S3;
    u16 *Qp = S4, *Kp = S5, *Vp = S6;
    u16 *VTb = S1, *Zf = S2, *o2 = S6;

    prep<<<dim3(2048, 1, 4), 256, 0, stream>>>(q, k, v, qb, kb, vb,
                                               Wq, Wk, Wv, Wo, wqT, wkT, wvT, woT);
    gemm_qkv<<<dim3(8, 32, 3), 256, 0, stream>>>(qb, kb, vb, wqT, wkT, wvT,
                                                 bq, bk, bv, Qp, Kp, Vp);
    vtrans<<<dim3(32, 32), 256, 0, stream>>>(Vp, VTb);
    z_kernel<<<dim3(32, 16, 2), 256, 0, stream>>>(Qp, Kp, Zf);
    attn_kernel<<<dim3(32, 16, 2), 256, 0, stream>>>(Qp, Kp, VTb, Zf, o2);
    gemm_out<<<dim3(8, 64), 256, 0, stream>>>(o2, woT, bo, out, NB * TS, HD, HD);
}